// Round 2
// baseline (290.369 us; speedup 1.0000x reference)
//
#include <hip/hip_runtime.h>

#define N_NODES 50000
#define N_EDGES 800000
#define BN_EPS 1e-5f

#define NBUCK 196        // ceil(50000/256) buckets of 256 nodes
#define PART_CAP 6016    // per-bucket capacity; mean 4082, sd 64 -> 30 sigma margin
#define PB 196           // partition blocks (ceil(800000/4096))
#define GB 196           // gemm0 blocks (ceil(50000/256), 256-row tiles)

// exclusive 256-thread scan in LDS; s[] is scratch (256 ints). Returns exclusive prefix.
__device__ __forceinline__ int lds_scan256_excl(int* s, int t, int v) {
    s[t] = v;
    __syncthreads();
    for (int off = 1; off < 256; off <<= 1) {
        int x = (t >= off) ? s[t - off] : 0;
        __syncthreads();
        s[t] += x;
        __syncthreads();
    }
    return s[t] - v;
}

// ---------------- GEMM0 body: Hs[r, 0..63] = X[r, 0..127] @ (W0 .* bn0scale[c]) ----------------
// 256-row tile; 256 threads = 8(tx) x 32(ty); each thread 8 rows (ty+32j) x 8 cols (tx*8..+7).
// LDS read ratio 16 b128 per 256 FMA (1:16) vs old 1:8 -> LDS floor halves.
__device__ __forceinline__ void gemm0_body(int bid, const float* __restrict__ X,
                                           const float* __restrict__ W,
                                           const float* __restrict__ gamma,
                                           const float* __restrict__ var,
                                           float* __restrict__ Hs, int n, float* lds) {
    constexpr int KC = 32;
    float* Xs = lds;               // 256 x 36 (pad 36: rows ty+32j -> banks 4*ty, conflict-free b128)
    float* Ws = lds + 256 * 36;    // 32 x 64
    const int tid = threadIdx.x;
    const int tx = tid & 7, ty = tid >> 3;
    const int row0 = bid * 256;
    const int c8 = tx * 8;
    float acc[8][8] = {};
    for (int k0 = 0; k0 < 128; k0 += KC) {
        // stage X tile: 256 rows x 32 k, float4 per thread x8 (coalesced 128B per 8 lanes)
#pragma unroll
        for (int it = 0; it < 8; ++it) {
            int idx = tid + it * 256;
            int r = idx >> 3, q = idx & 7;
            int row = row0 + r;
            float4 v = make_float4(0.f, 0.f, 0.f, 0.f);
            if (row < n) v = *(const float4*)&X[(size_t)row * 128 + k0 + q * 4];
            *(float4*)&Xs[r * 36 + q * 4] = v;
        }
        // stage W chunk with BN0 scale folded
#pragma unroll
        for (int it = 0; it < 8; ++it) {
            int i = tid + it * 256;
            int kk = i >> 6, c = i & 63;
            float w = W[(size_t)(k0 + kk) * 64 + c];
            w *= gamma[c] * rsqrtf(var[c] + BN_EPS);
            Ws[kk * 64 + c] = w;
        }
        __syncthreads();
#pragma unroll
        for (int kk0 = 0; kk0 < KC; kk0 += 4) {
            float4 av[8];
#pragma unroll
            for (int j = 0; j < 8; ++j)
                av[j] = *(const float4*)&Xs[(ty + 32 * j) * 36 + kk0];
#pragma unroll
            for (int q = 0; q < 4; ++q) {
                float4 b0 = *(const float4*)&Ws[(kk0 + q) * 64 + c8];
                float4 b1 = *(const float4*)&Ws[(kk0 + q) * 64 + c8 + 4];
#pragma unroll
                for (int j = 0; j < 8; ++j) {
                    float a = (&av[j].x)[q];
                    acc[j][0] += a * b0.x; acc[j][1] += a * b0.y;
                    acc[j][2] += a * b0.z; acc[j][3] += a * b0.w;
                    acc[j][4] += a * b1.x; acc[j][5] += a * b1.y;
                    acc[j][6] += a * b1.z; acc[j][7] += a * b1.w;
                }
            }
        }
        __syncthreads();
    }
#pragma unroll
    for (int j = 0; j < 8; ++j) {
        int r = row0 + ty + 32 * j;
        if (r < n) {
            *(float4*)&Hs[(size_t)r * 64 + c8] =
                make_float4(acc[j][0], acc[j][1], acc[j][2], acc[j][3]);
            *(float4*)&Hs[(size_t)r * 64 + c8 + 4] =
                make_float4(acc[j][4], acc[j][5], acc[j][6], acc[j][7]);
        }
    }
}

// ---------------- dispatch 2: gemm0 blocks FIRST (fat, 1/CU), then partition blocks ----------------
__global__ __launch_bounds__(256, 3)
void fused_gemm0_partition_kernel(const float* __restrict__ X, const float* __restrict__ W,
                                  const float* __restrict__ gamma, const float* __restrict__ var,
                                  float* __restrict__ Hs, int n,
                                  const int* __restrict__ src, const int* __restrict__ dst,
                                  int* __restrict__ gcur, unsigned int* __restrict__ part,
                                  int nE) {
    __shared__ float lds[256 * 36 + 32 * 64];   // 44 KB
    if (blockIdx.x < GB) {
        gemm0_body(blockIdx.x, X, W, gamma, var, Hs, n, lds);
        return;
    }
    // ---- partition branch: bin 4096 edges by dst>>8 ----
    int* lcnt  = (int*)lds;          // 196
    int* gbase = ((int*)lds) + 256;  // 196
    int t = threadIdx.x;
    int base = (blockIdx.x - GB) * 4096;
    for (int i = t; i < NBUCK; i += 256) lcnt[i] = 0;
    __syncthreads();
    unsigned int val[16], pk[16];
#pragma unroll
    for (int i = 0; i < 16; ++i) {
        int e = base + i * 256 + t;
        if (e < nE) {
            unsigned s = (unsigned)src[e], d = (unsigned)dst[e];
            unsigned b = d >> 8;
            int r = atomicAdd(&lcnt[b], 1);
            val[i] = s | ((d & 255u) << 16);
            pk[i] = b | ((unsigned)r << 8);
        } else pk[i] = 0xffffffffu;
    }
    __syncthreads();
    for (int i = t; i < NBUCK; i += 256) gbase[i] = atomicAdd(&gcur[i], lcnt[i]);
    __syncthreads();
#pragma unroll
    for (int i = 0; i < 16; ++i) {
        if (pk[i] != 0xffffffffu) {
            unsigned b = pk[i] & 255u;
            unsigned p = (unsigned)gbase[b] + (pk[i] >> 8);
            if (p < PART_CAP) part[b * PART_CAP + p] = val[i];
        }
    }
}

// ---------------- dispatch 3: per-bucket CSR build in LDS + dinv + Hs pre-scale ----------------
// Epilogue scales this bucket's 256 Hs rows by dinv[node], so the layer-1 gather needs no
// per-edge dinv loads (same trick layers 2/3 already use via pre-scaled outputs).
__global__ __launch_bounds__(256, 2)
void build_kernel(const unsigned int* __restrict__ part, const int* __restrict__ gcur,
                  int* __restrict__ rowptr, float* __restrict__ dinv,
                  unsigned short* __restrict__ csr, float* __restrict__ Hs, int n) {
    __shared__ int sc[256], nc[256], ns[256], cur[256];
    __shared__ float sdinv[256];
    __shared__ unsigned short csr_lds[PART_CAP];
    __shared__ int sh_off, sh_ec;
    int b = blockIdx.x, t = threadIdx.x;
    int v = (t < NBUCK) ? gcur[t] : 0;
    int ex = lds_scan256_excl(sc, t, v);
    if (t == b) { sh_off = ex; sh_ec = v; }
    nc[t] = 0;
    __syncthreads();
    int off = sh_off;
    int ec = sh_ec < PART_CAP ? sh_ec : PART_CAP;
    const unsigned int* pb = part + (size_t)b * PART_CAP;
    for (int i = t; i < ec; i += 256) atomicAdd(&nc[(pb[i] >> 16) & 255], 1);
    __syncthreads();
    int c = nc[t];
    int nx = lds_scan256_excl(ns, t, c);
    cur[t] = nx;
    float dv = rsqrtf((float)c + 1.0f);   // +1 = self loop
    sdinv[t] = dv;
    int node = b * 256 + t;
    if (node < n) {
        rowptr[node] = off + nx;
        dinv[node] = dv;
    }
    if (b == NBUCK - 1 && t == 0) rowptr[n] = off + ec;
    __syncthreads();
    for (int i = t; i < ec; i += 256) {
        unsigned w = pb[i];
        int p = atomicAdd(&cur[(w >> 16) & 255], 1);
        csr_lds[p] = (unsigned short)(w & 0xffffu);
    }
    __syncthreads();
    for (int i = t; i < ec; i += 256) csr[off + i] = csr_lds[i];
    // ---- pre-scale Hs rows of this bucket by dinv (sdinv synced above; no LDS hazard) ----
    float4* H4 = (float4*)(Hs + (size_t)b * 256 * 64);
    for (int i = t; i < 4096; i += 256) {
        int nd = i >> 4;
        if (b * 256 + nd < n) {
            float s = sdinv[nd];
            float4 x = H4[i];
            x.x *= s; x.y *= s; x.z *= s; x.w *= s;
            H4[i] = x;
        }
    }
}

// ---------------- fused gather (BN+ReLU) + next-layer GEMM ----------------
// block = 16 nodes x 16 lanes; input width 64; output width MOUT.
template <int MOUT, bool EDGE_SCALE, bool FOLD_NEXT>
__global__ __launch_bounds__(256, 6)
void gather_gemm_kernel(const float* __restrict__ Hs, const int* __restrict__ rowptr,
                        const unsigned short* __restrict__ csr, const float* __restrict__ dinv,
                        const float* __restrict__ b, const float* __restrict__ gamma,
                        const float* __restrict__ beta, const float* __restrict__ mean,
                        const float* __restrict__ var,
                        const float* __restrict__ Wn, const float* __restrict__ gn,
                        const float* __restrict__ vn, float* __restrict__ Hout, int n) {
    __shared__ float zs[16 * 64];
    __shared__ float Ws[64 * MOUT];
    int t = threadIdx.x;
    int nd = t >> 4, l = t & 15;
    int d = blockIdx.x * 16 + nd;           // grid exact: N % 16 == 0
    int c4 = l * 4;
    // stage next-layer W (BN-fold if requested)
    for (int i = t; i < 64 * MOUT; i += 256) {
        float w = Wn[i];
        if (FOLD_NEXT) { int c = i % MOUT; w *= gn[c] * rsqrtf(vn[c] + BN_EPS); }
        Ws[i] = w;
    }
    // ---- gather phase ----
    int beg = rowptr[d], end = rowptr[d + 1];
    float di = dinv[d];
    float4 acc = *(const float4*)&Hs[(size_t)d * 64 + c4];   // self loop (pre-scaled input)
    if (EDGE_SCALE) { acc.x *= di; acc.y *= di; acc.z *= di; acc.w *= di; }
    int e = beg;
    for (; e + 8 <= end; e += 8) {
        int sidx[8]; float4 vv[8]; float wgt[8];
#pragma unroll
        for (int q = 0; q < 8; ++q) sidx[q] = csr[e + q];
#pragma unroll
        for (int q = 0; q < 8; ++q) {
            vv[q] = *(const float4*)&Hs[(size_t)sidx[q] * 64 + c4];
            if (EDGE_SCALE) wgt[q] = dinv[sidx[q]];
        }
#pragma unroll
        for (int q = 0; q < 8; ++q) {
            float f = EDGE_SCALE ? wgt[q] : 1.0f;
            acc.x += vv[q].x * f; acc.y += vv[q].y * f;
            acc.z += vv[q].z * f; acc.w += vv[q].w * f;
        }
    }
    for (; e < end; ++e) {
        int s = csr[e];
        float4 vv = *(const float4*)&Hs[(size_t)s * 64 + c4];
        float f = EDGE_SCALE ? dinv[s] : 1.0f;
        acc.x += vv.x * f; acc.y += vv.y * f; acc.z += vv.z * f; acc.w += vv.w * f;
    }
    // BN bias + ReLU of current layer, write z tile to LDS
#pragma unroll
    for (int q = 0; q < 4; ++q) {
        int cc = c4 + q;
        float s0 = gamma[cc] * rsqrtf(var[cc] + BN_EPS);
        float bias = (b[cc] - mean[cc]) * s0 + beta[cc];
        float z = fmaxf((&acc.x)[q] * di + bias, 0.0f);
        zs[nd * 64 + cc] = z;
    }
    __syncthreads();
    // ---- gemm phase: Hout[d, c4..c4+3] = dinv[d] * sum_k zs[nd][k] * Ws[k][c] ----
    if (c4 < MOUT) {
        float o0 = 0.f, o1 = 0.f, o2 = 0.f, o3 = 0.f;
#pragma unroll 8
        for (int k = 0; k < 64; ++k) {
            float zk = zs[nd * 64 + k];
            float4 wv = *(const float4*)&Ws[k * MOUT + c4];
            o0 += zk * wv.x; o1 += zk * wv.y; o2 += zk * wv.z; o3 += zk * wv.w;
        }
        float4 r = make_float4(o0 * di, o1 * di, o2 * di, o3 * di);
        *(float4*)&Hout[(size_t)d * MOUT + c4] = r;
    }
}

// ---------------- final plain gather (M=40, bias only) ----------------
template <int M>
__global__ __launch_bounds__(256, 8)
void gather4_kernel(const float* __restrict__ Hs, const int* __restrict__ rowptr,
                    const unsigned short* __restrict__ csr, const float* __restrict__ dinv,
                    const float* __restrict__ bias, float* __restrict__ out, int n) {
    int t = threadIdx.x;
    int d = blockIdx.x * 16 + (t >> 4);
    int c4 = (t & 15) * 4;
    if (d >= n || c4 >= M) return;
    int beg = rowptr[d], end = rowptr[d + 1];
    float4 acc = *(const float4*)&Hs[(size_t)d * M + c4];
    int e = beg;
    for (; e + 8 <= end; e += 8) {
        int s0 = csr[e + 0], s1 = csr[e + 1], s2 = csr[e + 2], s3 = csr[e + 3];
        int s4 = csr[e + 4], s5 = csr[e + 5], s6 = csr[e + 6], s7 = csr[e + 7];
        float4 v0 = *(const float4*)&Hs[(size_t)s0 * M + c4];
        float4 v1 = *(const float4*)&Hs[(size_t)s1 * M + c4];
        float4 v2 = *(const float4*)&Hs[(size_t)s2 * M + c4];
        float4 v3 = *(const float4*)&Hs[(size_t)s3 * M + c4];
        float4 v4 = *(const float4*)&Hs[(size_t)s4 * M + c4];
        float4 v5 = *(const float4*)&Hs[(size_t)s5 * M + c4];
        float4 v6 = *(const float4*)&Hs[(size_t)s6 * M + c4];
        float4 v7 = *(const float4*)&Hs[(size_t)s7 * M + c4];
        acc.x += (v0.x + v1.x) + (v2.x + v3.x) + (v4.x + v5.x) + (v6.x + v7.x);
        acc.y += (v0.y + v1.y) + (v2.y + v3.y) + (v4.y + v5.y) + (v6.y + v7.y);
        acc.z += (v0.z + v1.z) + (v2.z + v3.z) + (v4.z + v5.z) + (v6.z + v7.z);
        acc.w += (v0.w + v1.w) + (v2.w + v3.w) + (v4.w + v5.w) + (v6.w + v7.w);
    }
    for (; e < end; ++e) {
        int s = csr[e];
        float4 v = *(const float4*)&Hs[(size_t)s * M + c4];
        acc.x += v.x; acc.y += v.y; acc.z += v.z; acc.w += v.w;
    }
    float di = dinv[d];
    float4 r;
    r.x = acc.x * di + bias[c4 + 0];
    r.y = acc.y * di + bias[c4 + 1];
    r.z = acc.z * di + bias[c4 + 2];
    r.w = acc.w * di + bias[c4 + 3];
    *(float4*)&out[(size_t)d * M + c4] = r;
}

extern "C" void kernel_launch(void* const* d_in, const int* in_sizes, int n_in,
                              void* d_out, int out_size, void* d_ws, size_t ws_size,
                              hipStream_t stream) {
    const float* x      = (const float*)d_in[0];
    const int*   ei     = (const int*)d_in[1];
    const float* W0     = (const float*)d_in[2];
    const float* b0     = (const float*)d_in[3];
    const float* gamma0 = (const float*)d_in[4];
    const float* beta0  = (const float*)d_in[5];
    const float* mean0  = (const float*)d_in[6];
    const float* var0   = (const float*)d_in[7];
    const float* W1     = (const float*)d_in[8];
    const float* b1     = (const float*)d_in[9];
    const float* gamma1 = (const float*)d_in[10];
    const float* beta1  = (const float*)d_in[11];
    const float* mean1  = (const float*)d_in[12];
    const float* var1   = (const float*)d_in[13];
    const float* W2     = (const float*)d_in[14];
    const float* b2     = (const float*)d_in[15];
    float* out = (float*)d_out;

    const int* srcp = ei;
    const int* dstp = ei + N_EDGES;
    const int N = N_NODES, E = N_EDGES;

    // workspace carve-up (bytes, 256-aligned)
    char* ws = (char*)d_ws;
    int*            gcur   = (int*)(ws + 0);          // 196*4
    int*            rowptr = (int*)(ws + 1024);       // 200004
    float*          dinv   = (float*)(ws + 202240);   // 200000
    unsigned short* csr    = (unsigned short*)(ws + 402688);  // 1600000
    float*          Hs     = (float*)(ws + 2002944);  // 12800000
    float*          buf    = (float*)(ws + 14802944); // 12800000
    unsigned int*   part   = (unsigned int*)buf;      // 196*6016*4 = 4.7 MB, dead after build

    hipMemsetAsync(gcur, 0, NBUCK * sizeof(int), stream);

    // d2: gemm0 (BN0-folded, unscaled, 256-row 8x8 tiles) + partition in one dispatch
    fused_gemm0_partition_kernel<<<GB + PB, 256, 0, stream>>>(
        x, W0, gamma0, var0, Hs, N, srcp, dstp, gcur, part, E);

    // d3: per-bucket CSR build + rowptr + dinv + Hs pre-scale (dinv[src] folded into rows)
    build_kernel<<<NBUCK, 256, 0, stream>>>(part, gcur, rowptr, dinv, csr, Hs, N);

    // d4: gather layer0 (plain sum of pre-scaled rows, BN0 bias+relu) + gemm1 (BN1-fold) -> buf
    gather_gemm_kernel<64, false, true><<<N / 16, 256, 0, stream>>>(
        Hs, rowptr, csr, dinv, b0, gamma0, beta0, mean0, var0,
        W1, gamma1, var1, buf, N);

    // d5: gather layer1 (plain, BN1 bias+relu) + gemm2 (raw W2) -> Hs
    gather_gemm_kernel<40, false, false><<<N / 16, 256, 0, stream>>>(
        buf, rowptr, csr, dinv, b1, gamma1, beta1, mean1, var1,
        W2, nullptr, nullptr, Hs, N);

    // d6: final plain gather + b2 -> out
    gather4_kernel<40><<<N / 16, 256, 0, stream>>>(Hs, rowptr, csr, dinv, b2, out, N);
}

// Round 3
// 284.689 us; speedup vs baseline: 1.0200x; 1.0200x over previous
//
#include <hip/hip_runtime.h>

#define N_NODES 50000
#define N_EDGES 800000
#define BN_EPS 1e-5f

#define NBUCK 196        // ceil(50000/256) buckets of 256 nodes
#define PART_CAP 6016    // per-bucket capacity; mean 4082, sd 64 -> 30 sigma margin
#define PB 196           // partition blocks (ceil(800000/4096))
#define GB 782           // gemm0 blocks (ceil(50000/64), 64-row tiles)

// exclusive 256-thread scan in LDS; s[] is scratch (256 ints). Returns exclusive prefix.
__device__ __forceinline__ int lds_scan256_excl(int* s, int t, int v) {
    s[t] = v;
    __syncthreads();
    for (int off = 1; off < 256; off <<= 1) {
        int x = (t >= off) ? s[t - off] : 0;
        __syncthreads();
        s[t] += x;
        __syncthreads();
    }
    return s[t] - v;
}

// ---------------- GEMM body: Hs[r,M] = X[r,K] @ (W .* foldscale[c]) ----------------
// 64-row tile; 256 threads = 16x16, each 4x4; K chunked by 32. (round-0 proven shape;
// 978-block grid keeps ~4 blocks/CU -> latency hidden. 8x8/256-row variant measured
// 76us @ 8% VALUBusy from parallelism collapse -- do not revisit without more blocks.)
template <int K, int M, bool FOLD>
__device__ __forceinline__ void gemm_body(int bid, const float* __restrict__ X,
                                          const float* __restrict__ W,
                                          const float* __restrict__ gamma,
                                          const float* __restrict__ var,
                                          float* __restrict__ Hs, int n, float* lds) {
    constexpr int KC = 32;
    float* Xs = lds;                    // 64 x 36
    float* Ws = lds + 64 * 36;          // 32 x M
    float* bns = lds + 64 * 36 + 32 * M; // M bn scales
    int tid = threadIdx.x;
    int tx = tid & 15, ty = tid >> 4;
    int row0 = bid * 64;
    if (FOLD && tid < M) bns[tid] = gamma[tid] * rsqrtf(var[tid] + BN_EPS);
    __syncthreads();
    float acc[4][4] = {};
    for (int k0 = 0; k0 < K; k0 += KC) {
        // stage X tile: 64 rows x 32 k as float4 (2 per thread)
#pragma unroll
        for (int it = 0; it < 2; ++it) {
            int fi = tid + it * 256;            // 512 float4s
            int r = fi >> 3, q = fi & 7;
            int row = row0 + r;
            float4 v = make_float4(0.f, 0.f, 0.f, 0.f);
            if (row < n) v = *(const float4*)&X[(size_t)row * K + k0 + q * 4];
            *(float4*)&Xs[r * 36 + q * 4] = v;
        }
        // stage W chunk as float4 (2 per thread), BN fold from LDS
#pragma unroll
        for (int it = 0; it < 2; ++it) {
            int fi = tid + it * 256;            // 512 float4s (32*M/4 with M=64)
            int kk = fi >> 4, cw = (fi & 15) * 4;
            float4 w = *(const float4*)&W[(size_t)(k0 + kk) * M + cw];
            if (FOLD) { w.x *= bns[cw]; w.y *= bns[cw + 1]; w.z *= bns[cw + 2]; w.w *= bns[cw + 3]; }
            *(float4*)&Ws[kk * M + cw] = w;
        }
        __syncthreads();
        if (tx * 4 < M) {
#pragma unroll 8
            for (int kk = 0; kk < KC; ++kk) {
                float4 bv = *(float4*)&Ws[kk * M + tx * 4];
#pragma unroll
                for (int j = 0; j < 4; ++j) {
                    float a = Xs[(ty * 4 + j) * 36 + kk];
                    acc[j][0] += a * bv.x;
                    acc[j][1] += a * bv.y;
                    acc[j][2] += a * bv.z;
                    acc[j][3] += a * bv.w;
                }
            }
        }
        __syncthreads();
    }
    if (tx * 4 < M) {
#pragma unroll
        for (int j = 0; j < 4; ++j) {
            int r = row0 + ty * 4 + j;
            if (r < n) {
                float4 v = make_float4(acc[j][0], acc[j][1], acc[j][2], acc[j][3]);
                *(float4*)&Hs[(size_t)r * M + tx * 4] = v;
            }
        }
    }
}

// ---------------- dispatch 2: partition blocks first, then gemm0 blocks ----------------
__global__ __launch_bounds__(256, 4)
void fused_gemm0_partition_kernel(const float* __restrict__ X, const float* __restrict__ W,
                                  const float* __restrict__ gamma, const float* __restrict__ var,
                                  float* __restrict__ Hs, int n,
                                  const int* __restrict__ src, const int* __restrict__ dst,
                                  int* __restrict__ gcur, unsigned int* __restrict__ part,
                                  int nE) {
    __shared__ float lds[64 * 36 + 32 * 64 + 64];   // 17.7 KB
    if (blockIdx.x >= PB) {
        gemm_body<128, 64, true>(blockIdx.x - PB, X, W, gamma, var, Hs, n, lds);
        return;
    }
    // ---- partition branch: bin 4096 edges by dst>>8 ----
    int* lcnt  = (int*)lds;          // 196
    int* gbase = ((int*)lds) + 256;  // 196
    int t = threadIdx.x;
    int base = blockIdx.x * 4096;
    for (int i = t; i < NBUCK; i += 256) lcnt[i] = 0;
    __syncthreads();
    unsigned int val[16], pk[16];
#pragma unroll
    for (int i = 0; i < 16; ++i) {
        int e = base + i * 256 + t;
        if (e < nE) {
            unsigned s = (unsigned)src[e], d = (unsigned)dst[e];
            unsigned b = d >> 8;
            int r = atomicAdd(&lcnt[b], 1);
            val[i] = s | ((d & 255u) << 16);
            pk[i] = b | ((unsigned)r << 8);
        } else pk[i] = 0xffffffffu;
    }
    __syncthreads();
    for (int i = t; i < NBUCK; i += 256) gbase[i] = atomicAdd(&gcur[i], lcnt[i]);
    __syncthreads();
#pragma unroll
    for (int i = 0; i < 16; ++i) {
        if (pk[i] != 0xffffffffu) {
            unsigned b = pk[i] & 255u;
            unsigned p = (unsigned)gbase[b] + (pk[i] >> 8);
            if (p < PART_CAP) part[b * PART_CAP + p] = val[i];
        }
    }
}

// ---------------- dispatch 3: per-bucket CSR build in LDS + dinv + Hs pre-scale ----------------
// Per-node edge lists are insertion-sorted by src: concurrently-resident gather blocks then
// walk src-ascending lists in loose lockstep -> hot src band stays closer to L2 capacity.
__global__ __launch_bounds__(256, 2)
void build_kernel(const unsigned int* __restrict__ part, const int* __restrict__ gcur,
                  int* __restrict__ rowptr, float* __restrict__ dinv,
                  unsigned short* __restrict__ csr, float* __restrict__ Hs, int n) {
    __shared__ int sc[256], nc[256], ns[256], cur[256];
    __shared__ float sdinv[256];
    __shared__ unsigned short csr_lds[PART_CAP];
    __shared__ int sh_off, sh_ec;
    int b = blockIdx.x, t = threadIdx.x;
    int v = (t < NBUCK) ? gcur[t] : 0;
    int ex = lds_scan256_excl(sc, t, v);
    if (t == b) { sh_off = ex; sh_ec = v; }
    nc[t] = 0;
    __syncthreads();
    int off = sh_off;
    int ec = sh_ec < PART_CAP ? sh_ec : PART_CAP;
    const unsigned int* pb = part + (size_t)b * PART_CAP;
    for (int i = t; i < ec; i += 256) atomicAdd(&nc[(pb[i] >> 16) & 255], 1);
    __syncthreads();
    int c = nc[t];
    int nx = lds_scan256_excl(ns, t, c);
    cur[t] = nx;
    float dv = rsqrtf((float)c + 1.0f);   // +1 = self loop
    sdinv[t] = dv;
    int node = b * 256 + t;
    if (node < n) {
        rowptr[node] = off + nx;
        dinv[node] = dv;
    }
    if (b == NBUCK - 1 && t == 0) rowptr[n] = off + ec;
    __syncthreads();
    for (int i = t; i < ec; i += 256) {
        unsigned w = pb[i];
        int p = atomicAdd(&cur[(w >> 16) & 255], 1);
        csr_lds[p] = (unsigned short)(w & 0xffffu);
    }
    __syncthreads();
    // ---- sort own node's sublist by src (ranges disjoint per thread) ----
    {
        int s0 = nx, s1 = nx + c;
        for (int i = s0 + 1; i < s1; ++i) {
            unsigned short key = csr_lds[i];
            int j = i - 1;
            while (j >= s0 && csr_lds[j] > key) { csr_lds[j + 1] = csr_lds[j]; --j; }
            csr_lds[j + 1] = key;
        }
    }
    __syncthreads();
    for (int i = t; i < ec; i += 256) csr[off + i] = csr_lds[i];
    // ---- pre-scale Hs rows of this bucket by dinv ----
    float4* H4 = (float4*)(Hs + (size_t)b * 256 * 64);
    for (int i = t; i < 4096; i += 256) {
        int nd = i >> 4;
        if (b * 256 + nd < n) {
            float s = sdinv[nd];
            float4 x = H4[i];
            x.x *= s; x.y *= s; x.z *= s; x.w *= s;
            H4[i] = x;
        }
    }
}

// ---------------- fused gather (BN+ReLU) + next-layer GEMM ----------------
// block = 16 nodes x 16 lanes; input width 64 (dinv-prefolded rows); output width MOUT.
template <int MOUT, bool FOLD_NEXT>
__global__ __launch_bounds__(256, 6)
void gather_gemm_kernel(const float* __restrict__ Hs, const int* __restrict__ rowptr,
                        const unsigned short* __restrict__ csr, const float* __restrict__ dinv,
                        const float* __restrict__ b, const float* __restrict__ gamma,
                        const float* __restrict__ beta, const float* __restrict__ mean,
                        const float* __restrict__ var,
                        const float* __restrict__ Wn, const float* __restrict__ gn,
                        const float* __restrict__ vn, float* __restrict__ Hout, int n) {
    __shared__ float zs[16 * 64];
    __shared__ float Ws[64 * MOUT];
    int t = threadIdx.x;
    int nd = t >> 4, l = t & 15;
    int d = blockIdx.x * 16 + nd;           // grid exact: N % 16 == 0
    int c4 = l * 4;
    // stage next-layer W (BN-fold if requested)
    for (int i = t; i < 64 * MOUT; i += 256) {
        float w = Wn[i];
        if (FOLD_NEXT) { int c = i % MOUT; w *= gn[c] * rsqrtf(vn[c] + BN_EPS); }
        Ws[i] = w;
    }
    // ---- gather phase (plain sum of pre-scaled rows) ----
    int beg = rowptr[d], end = rowptr[d + 1];
    float di = dinv[d];
    float4 acc = *(const float4*)&Hs[(size_t)d * 64 + c4];   // self loop
    int e = beg;
    int head = (beg + 7) & ~7;               // align for uint4 index loads
    if (head > end) head = end;
    for (; e < head; ++e) {
        int s = csr[e];
        float4 vv = *(const float4*)&Hs[(size_t)s * 64 + c4];
        acc.x += vv.x; acc.y += vv.y; acc.z += vv.z; acc.w += vv.w;
    }
    for (; e + 8 <= end; e += 8) {
        uint4 iv = *(const uint4*)&csr[e];   // 8 indices in one 16B load
        int sidx[8];
        sidx[0] = iv.x & 0xffff; sidx[1] = iv.x >> 16;
        sidx[2] = iv.y & 0xffff; sidx[3] = iv.y >> 16;
        sidx[4] = iv.z & 0xffff; sidx[5] = iv.z >> 16;
        sidx[6] = iv.w & 0xffff; sidx[7] = iv.w >> 16;
        float4 vv[8];
#pragma unroll
        for (int q = 0; q < 8; ++q)
            vv[q] = *(const float4*)&Hs[(size_t)sidx[q] * 64 + c4];
#pragma unroll
        for (int q = 0; q < 8; ++q) {
            acc.x += vv[q].x; acc.y += vv[q].y;
            acc.z += vv[q].z; acc.w += vv[q].w;
        }
    }
    for (; e < end; ++e) {
        int s = csr[e];
        float4 vv = *(const float4*)&Hs[(size_t)s * 64 + c4];
        acc.x += vv.x; acc.y += vv.y; acc.z += vv.z; acc.w += vv.w;
    }
    // BN bias + ReLU of current layer, write z tile to LDS
#pragma unroll
    for (int q = 0; q < 4; ++q) {
        int cc = c4 + q;
        float s0 = gamma[cc] * rsqrtf(var[cc] + BN_EPS);
        float bias = (b[cc] - mean[cc]) * s0 + beta[cc];
        float z = fmaxf((&acc.x)[q] * di + bias, 0.0f);
        zs[nd * 64 + cc] = z;
    }
    __syncthreads();
    // ---- gemm phase: Hout[d, c4..c4+3] = dinv[d] * sum_k zs[nd][k] * Ws[k][c] ----
    if (c4 < MOUT) {
        float o0 = 0.f, o1 = 0.f, o2 = 0.f, o3 = 0.f;
#pragma unroll 8
        for (int k = 0; k < 64; ++k) {
            float zk = zs[nd * 64 + k];
            float4 wv = *(const float4*)&Ws[k * MOUT + c4];
            o0 += zk * wv.x; o1 += zk * wv.y; o2 += zk * wv.z; o3 += zk * wv.w;
        }
        float4 r = make_float4(o0 * di, o1 * di, o2 * di, o3 * di);
        *(float4*)&Hout[(size_t)d * MOUT + c4] = r;
    }
}

// ---------------- final plain gather (M=40, bias only) ----------------
template <int M>
__global__ __launch_bounds__(256, 8)
void gather4_kernel(const float* __restrict__ Hs, const int* __restrict__ rowptr,
                    const unsigned short* __restrict__ csr, const float* __restrict__ dinv,
                    const float* __restrict__ bias, float* __restrict__ out, int n) {
    int t = threadIdx.x;
    int d = blockIdx.x * 16 + (t >> 4);
    int c4 = (t & 15) * 4;
    if (d >= n || c4 >= M) return;
    int beg = rowptr[d], end = rowptr[d + 1];
    float4 acc = *(const float4*)&Hs[(size_t)d * M + c4];
    int e = beg;
    int head = (beg + 7) & ~7;
    if (head > end) head = end;
    for (; e < head; ++e) {
        int s = csr[e];
        float4 v = *(const float4*)&Hs[(size_t)s * M + c4];
        acc.x += v.x; acc.y += v.y; acc.z += v.z; acc.w += v.w;
    }
    for (; e + 8 <= end; e += 8) {
        uint4 iv = *(const uint4*)&csr[e];
        int s0 = iv.x & 0xffff, s1 = iv.x >> 16;
        int s2 = iv.y & 0xffff, s3 = iv.y >> 16;
        int s4 = iv.z & 0xffff, s5 = iv.z >> 16;
        int s6 = iv.w & 0xffff, s7 = iv.w >> 16;
        float4 v0 = *(const float4*)&Hs[(size_t)s0 * M + c4];
        float4 v1 = *(const float4*)&Hs[(size_t)s1 * M + c4];
        float4 v2 = *(const float4*)&Hs[(size_t)s2 * M + c4];
        float4 v3 = *(const float4*)&Hs[(size_t)s3 * M + c4];
        float4 v4 = *(const float4*)&Hs[(size_t)s4 * M + c4];
        float4 v5 = *(const float4*)&Hs[(size_t)s5 * M + c4];
        float4 v6 = *(const float4*)&Hs[(size_t)s6 * M + c4];
        float4 v7 = *(const float4*)&Hs[(size_t)s7 * M + c4];
        acc.x += (v0.x + v1.x) + (v2.x + v3.x) + (v4.x + v5.x) + (v6.x + v7.x);
        acc.y += (v0.y + v1.y) + (v2.y + v3.y) + (v4.y + v5.y) + (v6.y + v7.y);
        acc.z += (v0.z + v1.z) + (v2.z + v3.z) + (v4.z + v5.z) + (v6.z + v7.z);
        acc.w += (v0.w + v1.w) + (v2.w + v3.w) + (v4.w + v5.w) + (v6.w + v7.w);
    }
    for (; e < end; ++e) {
        int s = csr[e];
        float4 v = *(const float4*)&Hs[(size_t)s * M + c4];
        acc.x += v.x; acc.y += v.y; acc.z += v.z; acc.w += v.w;
    }
    float di = dinv[d];
    float4 r;
    r.x = acc.x * di + bias[c4 + 0];
    r.y = acc.y * di + bias[c4 + 1];
    r.z = acc.z * di + bias[c4 + 2];
    r.w = acc.w * di + bias[c4 + 3];
    *(float4*)&out[(size_t)d * M + c4] = r;
}

extern "C" void kernel_launch(void* const* d_in, const int* in_sizes, int n_in,
                              void* d_out, int out_size, void* d_ws, size_t ws_size,
                              hipStream_t stream) {
    const float* x      = (const float*)d_in[0];
    const int*   ei     = (const int*)d_in[1];
    const float* W0     = (const float*)d_in[2];
    const float* b0     = (const float*)d_in[3];
    const float* gamma0 = (const float*)d_in[4];
    const float* beta0  = (const float*)d_in[5];
    const float* mean0  = (const float*)d_in[6];
    const float* var0   = (const float*)d_in[7];
    const float* W1     = (const float*)d_in[8];
    const float* b1     = (const float*)d_in[9];
    const float* gamma1 = (const float*)d_in[10];
    const float* beta1  = (const float*)d_in[11];
    const float* mean1  = (const float*)d_in[12];
    const float* var1   = (const float*)d_in[13];
    const float* W2     = (const float*)d_in[14];
    const float* b2     = (const float*)d_in[15];
    float* out = (float*)d_out;

    const int* srcp = ei;
    const int* dstp = ei + N_EDGES;
    const int N = N_NODES, E = N_EDGES;

    // workspace carve-up (bytes, 256-aligned)
    char* ws = (char*)d_ws;
    int*            gcur   = (int*)(ws + 0);          // 196*4
    int*            rowptr = (int*)(ws + 1024);       // 200004
    float*          dinv   = (float*)(ws + 202240);   // 200000
    unsigned short* csr    = (unsigned short*)(ws + 402688);  // 1600000 (16B-aligned)
    float*          Hs     = (float*)(ws + 2002944);  // 12800000
    float*          buf    = (float*)(ws + 14802944); // 12800000
    unsigned int*   part   = (unsigned int*)buf;      // 196*6016*4 = 4.7 MB, dead after build

    hipMemsetAsync(gcur, 0, NBUCK * sizeof(int), stream);

    // d2: partition (blocks 0..195) + gemm0 (BN0-folded, 64-row tiles) in one dispatch
    fused_gemm0_partition_kernel<<<PB + GB, 256, 0, stream>>>(
        x, W0, gamma0, var0, Hs, N, srcp, dstp, gcur, part, E);

    // d3: per-bucket CSR build (src-sorted lists) + rowptr + dinv + Hs dinv-prefold
    build_kernel<<<NBUCK, 256, 0, stream>>>(part, gcur, rowptr, dinv, csr, Hs, N);

    // d4: gather layer0 (plain sum, BN0 bias+relu) + gemm1 (BN1-scale folded) -> buf
    gather_gemm_kernel<64, true><<<N / 16, 256, 0, stream>>>(
        Hs, rowptr, csr, dinv, b0, gamma0, beta0, mean0, var0,
        W1, gamma1, var1, buf, N);

    // d5: gather layer1 (plain, BN1 bias+relu) + gemm2 (raw W2) -> Hs
    gather_gemm_kernel<40, false><<<N / 16, 256, 0, stream>>>(
        buf, rowptr, csr, dinv, b1, gamma1, beta1, mean1, var1,
        W2, nullptr, nullptr, Hs, N);

    // d6: final plain gather + b2 -> out
    gather4_kernel<40><<<N / 16, 256, 0, stream>>>(Hs, rowptr, csr, dinv, b2, out, N);
}

// Round 4
// 234.610 us; speedup vs baseline: 1.2377x; 1.2135x over previous
//
#include <hip/hip_runtime.h>
#include <hip/hip_fp16.h>

#define N_NODES 50000
#define N_EDGES 800000
#define BN_EPS 1e-5f

#define NBUCK 196        // ceil(50000/256) buckets of 256 nodes
#define PART_CAP 6016    // per-bucket capacity; mean 4082, sd 64 -> 30 sigma margin
#define PB 196           // partition blocks (ceil(800000/4096))
#define GB 782           // gemm0 blocks (ceil(50000/64), 64-row tiles)

// exclusive 256-thread scan in LDS; s[] is scratch (256 ints). Returns exclusive prefix.
__device__ __forceinline__ int lds_scan256_excl(int* s, int t, int v) {
    s[t] = v;
    __syncthreads();
    for (int off = 1; off < 256; off <<= 1) {
        int x = (t >= off) ? s[t - off] : 0;
        __syncthreads();
        s[t] += x;
        __syncthreads();
    }
    return s[t] - v;
}

// ---------------- GEMM body: Hs[r,M] = X[r,K] @ (W .* foldscale[c]) ----------------
// 64-row tile; 256 threads = 16x16, each 4x4; K chunked by 32. (proven shape: 978-block
// grid keeps ~4 blocks/CU. 8x8/256-row variant measured 76us @ 8% VALUBusy from
// parallelism collapse -- do not revisit.)
template <int K, int M, bool FOLD>
__device__ __forceinline__ void gemm_body(int bid, const float* __restrict__ X,
                                          const float* __restrict__ W,
                                          const float* __restrict__ gamma,
                                          const float* __restrict__ var,
                                          float* __restrict__ Hs, int n, float* lds) {
    constexpr int KC = 32;
    float* Xs = lds;                    // 64 x 36
    float* Ws = lds + 64 * 36;          // 32 x M
    float* bns = lds + 64 * 36 + 32 * M; // M bn scales
    int tid = threadIdx.x;
    int tx = tid & 15, ty = tid >> 4;
    int row0 = bid * 64;
    if (FOLD && tid < M) bns[tid] = gamma[tid] * rsqrtf(var[tid] + BN_EPS);
    __syncthreads();
    float acc[4][4] = {};
    for (int k0 = 0; k0 < K; k0 += KC) {
#pragma unroll
        for (int it = 0; it < 2; ++it) {
            int fi = tid + it * 256;            // 512 float4s
            int r = fi >> 3, q = fi & 7;
            int row = row0 + r;
            float4 v = make_float4(0.f, 0.f, 0.f, 0.f);
            if (row < n) v = *(const float4*)&X[(size_t)row * K + k0 + q * 4];
            *(float4*)&Xs[r * 36 + q * 4] = v;
        }
#pragma unroll
        for (int it = 0; it < 2; ++it) {
            int fi = tid + it * 256;            // 512 float4s (32*M/4 with M=64)
            int kk = fi >> 4, cw = (fi & 15) * 4;
            float4 w = *(const float4*)&W[(size_t)(k0 + kk) * M + cw];
            if (FOLD) { w.x *= bns[cw]; w.y *= bns[cw + 1]; w.z *= bns[cw + 2]; w.w *= bns[cw + 3]; }
            *(float4*)&Ws[kk * M + cw] = w;
        }
        __syncthreads();
        if (tx * 4 < M) {
#pragma unroll 8
            for (int kk = 0; kk < KC; ++kk) {
                float4 bv = *(float4*)&Ws[kk * M + tx * 4];
#pragma unroll
                for (int j = 0; j < 4; ++j) {
                    float a = Xs[(ty * 4 + j) * 36 + kk];
                    acc[j][0] += a * bv.x;
                    acc[j][1] += a * bv.y;
                    acc[j][2] += a * bv.z;
                    acc[j][3] += a * bv.w;
                }
            }
        }
        __syncthreads();
    }
    if (tx * 4 < M) {
#pragma unroll
        for (int j = 0; j < 4; ++j) {
            int r = row0 + ty * 4 + j;
            if (r < n) {
                float4 v = make_float4(acc[j][0], acc[j][1], acc[j][2], acc[j][3]);
                *(float4*)&Hs[(size_t)r * M + tx * 4] = v;
            }
        }
    }
}

// ---------------- dispatch 2: partition blocks first, then gemm0 blocks ----------------
__global__ __launch_bounds__(256, 4)
void fused_gemm0_partition_kernel(const float* __restrict__ X, const float* __restrict__ W,
                                  const float* __restrict__ gamma, const float* __restrict__ var,
                                  float* __restrict__ Hs, int n,
                                  const int* __restrict__ src, const int* __restrict__ dst,
                                  int* __restrict__ gcur, unsigned int* __restrict__ part,
                                  int nE) {
    __shared__ float lds[64 * 36 + 32 * 64 + 64];   // 17.7 KB
    if (blockIdx.x >= PB) {
        gemm_body<128, 64, true>(blockIdx.x - PB, X, W, gamma, var, Hs, n, lds);
        return;
    }
    // ---- partition branch: bin 4096 edges by dst>>8 ----
    int* lcnt  = (int*)lds;          // 196
    int* gbase = ((int*)lds) + 256;  // 196
    int t = threadIdx.x;
    int base = blockIdx.x * 4096;
    for (int i = t; i < NBUCK; i += 256) lcnt[i] = 0;
    __syncthreads();
    unsigned int val[16], pk[16];
#pragma unroll
    for (int i = 0; i < 16; ++i) {
        int e = base + i * 256 + t;
        if (e < nE) {
            unsigned s = (unsigned)src[e], d = (unsigned)dst[e];
            unsigned b = d >> 8;
            int r = atomicAdd(&lcnt[b], 1);
            val[i] = s | ((d & 255u) << 16);
            pk[i] = b | ((unsigned)r << 8);
        } else pk[i] = 0xffffffffu;
    }
    __syncthreads();
    for (int i = t; i < NBUCK; i += 256) gbase[i] = atomicAdd(&gcur[i], lcnt[i]);
    __syncthreads();
#pragma unroll
    for (int i = 0; i < 16; ++i) {
        if (pk[i] != 0xffffffffu) {
            unsigned b = pk[i] & 255u;
            unsigned p = (unsigned)gbase[b] + (pk[i] >> 8);
            if (p < PART_CAP) part[b * PART_CAP + p] = val[i];
        }
    }
}

// ---------------- dispatch 3: per-bucket CSR build + rowptr + dinv + fp16 prescaled table ----
// (NO per-node sort: measured +50us serial/divergent cost, ~0 gather benefit on random graph.)
__global__ __launch_bounds__(256, 2)
void build_kernel(const unsigned int* __restrict__ part, const int* __restrict__ gcur,
                  int* __restrict__ rowptr, float* __restrict__ dinv,
                  unsigned short* __restrict__ csr, const float* __restrict__ Hs,
                  __half* __restrict__ Hh, int n) {
    __shared__ int sc[256], nc[256], ns[256], cur[256];
    __shared__ float sdinv[256];
    __shared__ unsigned short csr_lds[PART_CAP];
    __shared__ int sh_off, sh_ec;
    int b = blockIdx.x, t = threadIdx.x;
    int v = (t < NBUCK) ? gcur[t] : 0;
    int ex = lds_scan256_excl(sc, t, v);
    if (t == b) { sh_off = ex; sh_ec = v; }
    nc[t] = 0;
    __syncthreads();
    int off = sh_off;
    int ec = sh_ec < PART_CAP ? sh_ec : PART_CAP;
    const unsigned int* pb = part + (size_t)b * PART_CAP;
    for (int i = t; i < ec; i += 256) atomicAdd(&nc[(pb[i] >> 16) & 255], 1);
    __syncthreads();
    int c = nc[t];
    int nx = lds_scan256_excl(ns, t, c);
    cur[t] = nx;
    float dv = rsqrtf((float)c + 1.0f);   // +1 = self loop
    sdinv[t] = dv;
    int node = b * 256 + t;
    if (node < n) {
        rowptr[node] = off + nx;
        dinv[node] = dv;
    }
    if (b == NBUCK - 1 && t == 0) rowptr[n] = off + ec;
    __syncthreads();
    for (int i = t; i < ec; i += 256) {
        unsigned w = pb[i];
        int p = atomicAdd(&cur[(w >> 16) & 255], 1);
        csr_lds[p] = (unsigned short)(w & 0xffffu);
    }
    __syncthreads();
    for (int i = t; i < ec; i += 256) csr[off + i] = csr_lds[i];
    // ---- convert this bucket's Hs rows to fp16 with dinv prefold ----
    const float4* H4 = (const float4*)(Hs + (size_t)b * 256 * 64);
    for (int i = t; i < 4096; i += 256) {
        int nd = i >> 4;
        int nn = b * 256 + nd;
        if (nn < n) {
            float s = sdinv[nd];
            float4 x = H4[i];
            union { uint2 u; __half2 h[2]; } U;
            U.h[0] = __floats2half2_rn(x.x * s, x.y * s);
            U.h[1] = __floats2half2_rn(x.z * s, x.w * s);
            *(uint2*)&Hh[(size_t)nn * 64 + (i & 15) * 4] = U.u;
        }
    }
}

// ---------------- fused gather (fp16 table, BN+ReLU) + next-layer GEMM ----------------
// block = 32 nodes x 8 lanes; each lane owns 8 channels (16B fp16 loads).
template <int MOUT, bool FOLD_NEXT>
__global__ __launch_bounds__(256, 6)
void gather_gemm_h(const __half* __restrict__ Hh, const int* __restrict__ rowptr,
                   const unsigned short* __restrict__ csr, const float* __restrict__ dinv,
                   const float* __restrict__ bb, const float* __restrict__ gamma,
                   const float* __restrict__ beta, const float* __restrict__ mean,
                   const float* __restrict__ var,
                   const float* __restrict__ Wn, const float* __restrict__ gn,
                   const float* __restrict__ vn, __half* __restrict__ Hout, int n) {
    __shared__ float zs[32 * 68];          // pad 68: 8 nodes/wave -> conflict-free z reads
    __shared__ float Ws[64 * MOUT];
    int t = threadIdx.x;
    int nd = t >> 3, l = t & 7;
    int d = blockIdx.x * 32 + nd;
    int c8 = l * 8;
    for (int i = t; i < 64 * MOUT; i += 256) {
        float w = Wn[i];
        if (FOLD_NEXT) { int c = i % MOUT; w *= gn[c] * rsqrtf(vn[c] + BN_EPS); }
        Ws[i] = w;
    }
    float acc[8] = {};
    float di = 0.f;
    int beg = 0, end = 0;
    if (d < n) {
        beg = rowptr[d]; end = rowptr[d + 1];
        di = dinv[d];
        union { uint4 u; __half2 h[4]; } S;
        S.u = *(const uint4*)&Hh[(size_t)d * 64 + c8];   // self loop (prescaled)
#pragma unroll
        for (int p = 0; p < 4; ++p) {
            float2 f = __half22float2(S.h[p]);
            acc[2 * p] += f.x; acc[2 * p + 1] += f.y;
        }
    }
    int e = beg;
    int head = (beg + 7) & ~7;             // align for uint4 index loads
    if (head > end) head = end;
    for (; e < head; ++e) {
        int s = csr[e];
        union { uint4 u; __half2 h[4]; } V;
        V.u = *(const uint4*)&Hh[(size_t)s * 64 + c8];
#pragma unroll
        for (int p = 0; p < 4; ++p) {
            float2 f = __half22float2(V.h[p]);
            acc[2 * p] += f.x; acc[2 * p + 1] += f.y;
        }
    }
    for (; e + 8 <= end; e += 8) {
        uint4 iv = *(const uint4*)&csr[e];   // 8 indices in one 16B load
        int sidx[8];
        sidx[0] = iv.x & 0xffff; sidx[1] = iv.x >> 16;
        sidx[2] = iv.y & 0xffff; sidx[3] = iv.y >> 16;
        sidx[4] = iv.z & 0xffff; sidx[5] = iv.z >> 16;
        sidx[6] = iv.w & 0xffff; sidx[7] = iv.w >> 16;
        uint4 vv[8];
#pragma unroll
        for (int q = 0; q < 8; ++q)
            vv[q] = *(const uint4*)&Hh[(size_t)sidx[q] * 64 + c8];
#pragma unroll
        for (int q = 0; q < 8; ++q) {
            union { uint4 u; __half2 h[4]; } V; V.u = vv[q];
#pragma unroll
            for (int p = 0; p < 4; ++p) {
                float2 f = __half22float2(V.h[p]);
                acc[2 * p] += f.x; acc[2 * p + 1] += f.y;
            }
        }
    }
    for (; e < end; ++e) {
        int s = csr[e];
        union { uint4 u; __half2 h[4]; } V;
        V.u = *(const uint4*)&Hh[(size_t)s * 64 + c8];
#pragma unroll
        for (int p = 0; p < 4; ++p) {
            float2 f = __half22float2(V.h[p]);
            acc[2 * p] += f.x; acc[2 * p + 1] += f.y;
        }
    }
    // BN bias + ReLU of current layer, write z tile to LDS
    if (d < n) {
#pragma unroll
        for (int q = 0; q < 8; ++q) {
            int cc = c8 + q;
            float s0 = gamma[cc] * rsqrtf(var[cc] + BN_EPS);
            float bias = (bb[cc] - mean[cc]) * s0 + beta[cc];
            zs[nd * 68 + cc] = fmaxf(acc[q] * di + bias, 0.0f);
        }
    }
    __syncthreads();
    // ---- gemm phase: Hout[d, c8..c8+7] = fp16(dinv[d] * sum_k zs[nd][k] * Ws[k][c]) ----
    if (c8 < MOUT && d < n) {
        float o[8] = {};
        for (int k0 = 0; k0 < 64; k0 += 4) {
            float4 zq = *(const float4*)&zs[nd * 68 + k0];
#pragma unroll
            for (int j = 0; j < 4; ++j) {
                float zk = (&zq.x)[j];
                float4 w0 = *(const float4*)&Ws[(k0 + j) * MOUT + c8];
                float4 w1 = *(const float4*)&Ws[(k0 + j) * MOUT + c8 + 4];
                o[0] += zk * w0.x; o[1] += zk * w0.y; o[2] += zk * w0.z; o[3] += zk * w0.w;
                o[4] += zk * w1.x; o[5] += zk * w1.y; o[6] += zk * w1.z; o[7] += zk * w1.w;
            }
        }
        union { uint4 u; __half2 h[4]; } O;
#pragma unroll
        for (int p = 0; p < 4; ++p)
            O.h[p] = __floats2half2_rn(o[2 * p] * di, o[2 * p + 1] * di);
        *(uint4*)&Hout[(size_t)d * MOUT + c8] = O.u;
    }
}

// ---------------- final gather over fp16 40-ch rows; fp32 out ----------------
// block = 50 nodes x 5 lanes (250 active threads); lane owns 8 channels (16B loads).
__global__ __launch_bounds__(256, 8)
void gather_out_kernel(const __half* __restrict__ t3, const int* __restrict__ rowptr,
                       const unsigned short* __restrict__ csr, const float* __restrict__ dinv,
                       const float* __restrict__ bias, float* __restrict__ out, int n) {
    int t = threadIdx.x;
    if (t >= 250) return;
    int nd = t / 5, l = t % 5;
    int d = blockIdx.x * 50 + nd;
    if (d >= n) return;
    int c8 = l * 8;
    int beg = rowptr[d], end = rowptr[d + 1];
    float di = dinv[d];
    float acc[8];
    {
        union { uint4 u; __half2 h[4]; } S;
        S.u = *(const uint4*)&t3[(size_t)d * 40 + c8];
#pragma unroll
        for (int p = 0; p < 4; ++p) {
            float2 f = __half22float2(S.h[p]);
            acc[2 * p] = f.x; acc[2 * p + 1] = f.y;
        }
    }
    int e = beg;
    int head = (beg + 7) & ~7;
    if (head > end) head = end;
    for (; e < head; ++e) {
        int s = csr[e];
        union { uint4 u; __half2 h[4]; } V;
        V.u = *(const uint4*)&t3[(size_t)s * 40 + c8];
#pragma unroll
        for (int p = 0; p < 4; ++p) {
            float2 f = __half22float2(V.h[p]);
            acc[2 * p] += f.x; acc[2 * p + 1] += f.y;
        }
    }
    for (; e + 8 <= end; e += 8) {
        uint4 iv = *(const uint4*)&csr[e];
        int sidx[8];
        sidx[0] = iv.x & 0xffff; sidx[1] = iv.x >> 16;
        sidx[2] = iv.y & 0xffff; sidx[3] = iv.y >> 16;
        sidx[4] = iv.z & 0xffff; sidx[5] = iv.z >> 16;
        sidx[6] = iv.w & 0xffff; sidx[7] = iv.w >> 16;
        uint4 vv[8];
#pragma unroll
        for (int q = 0; q < 8; ++q)
            vv[q] = *(const uint4*)&t3[(size_t)sidx[q] * 40 + c8];
#pragma unroll
        for (int q = 0; q < 8; ++q) {
            union { uint4 u; __half2 h[4]; } V; V.u = vv[q];
#pragma unroll
            for (int p = 0; p < 4; ++p) {
                float2 f = __half22float2(V.h[p]);
                acc[2 * p] += f.x; acc[2 * p + 1] += f.y;
            }
        }
    }
    for (; e < end; ++e) {
        int s = csr[e];
        union { uint4 u; __half2 h[4]; } V;
        V.u = *(const uint4*)&t3[(size_t)s * 40 + c8];
#pragma unroll
        for (int p = 0; p < 4; ++p) {
            float2 f = __half22float2(V.h[p]);
            acc[2 * p] += f.x; acc[2 * p + 1] += f.y;
        }
    }
    float4 r0, r1;
    r0.x = acc[0] * di + bias[c8 + 0];
    r0.y = acc[1] * di + bias[c8 + 1];
    r0.z = acc[2] * di + bias[c8 + 2];
    r0.w = acc[3] * di + bias[c8 + 3];
    r1.x = acc[4] * di + bias[c8 + 4];
    r1.y = acc[5] * di + bias[c8 + 5];
    r1.z = acc[6] * di + bias[c8 + 6];
    r1.w = acc[7] * di + bias[c8 + 7];
    *(float4*)&out[(size_t)d * 40 + c8] = r0;
    *(float4*)&out[(size_t)d * 40 + c8 + 4] = r1;
}

extern "C" void kernel_launch(void* const* d_in, const int* in_sizes, int n_in,
                              void* d_out, int out_size, void* d_ws, size_t ws_size,
                              hipStream_t stream) {
    const float* x      = (const float*)d_in[0];
    const int*   ei     = (const int*)d_in[1];
    const float* W0     = (const float*)d_in[2];
    const float* b0     = (const float*)d_in[3];
    const float* gamma0 = (const float*)d_in[4];
    const float* beta0  = (const float*)d_in[5];
    const float* mean0  = (const float*)d_in[6];
    const float* var0   = (const float*)d_in[7];
    const float* W1     = (const float*)d_in[8];
    const float* b1     = (const float*)d_in[9];
    const float* gamma1 = (const float*)d_in[10];
    const float* beta1  = (const float*)d_in[11];
    const float* mean1  = (const float*)d_in[12];
    const float* var1   = (const float*)d_in[13];
    const float* W2     = (const float*)d_in[14];
    const float* b2     = (const float*)d_in[15];
    float* out = (float*)d_out;

    const int* srcp = ei;
    const int* dstp = ei + N_EDGES;
    const int N = N_NODES, E = N_EDGES;

    // workspace carve-up (bytes, 16B-aligned). Total footprint 27.6 MB (same as prior rounds).
    char* ws = (char*)d_ws;
    int*            gcur   = (int*)(ws + 0);          // 784 B
    int*            rowptr = (int*)(ws + 1024);       // 200004
    float*          dinv   = (float*)(ws + 202240);   // 200000
    unsigned short* csr    = (unsigned short*)(ws + 402688);   // 1.6 MB
    float*          Hs     = (float*)(ws + 2002944);  // 12.8 MB fp32 gemm0 out (dead after d3)
    __half*         bufh   = (__half*)(ws + 2002944); // 6.4 MB, aliases Hs (written in d4)
    __half*         t3h    = (__half*)(ws + 8402944); // 4.0 MB, aliases Hs tail (written in d5)
    unsigned int*   part   = (unsigned int*)(ws + 14802944);   // 4.7 MB (dead after d3)
    __half*         Hh     = (__half*)(ws + 21202944);         // 6.4 MB fp16 prescaled layer-1 table

    hipMemsetAsync(gcur, 0, NBUCK * sizeof(int), stream);

    // d2: partition (blocks 0..195) + gemm0 (BN0-folded, 64-row tiles) in one dispatch
    fused_gemm0_partition_kernel<<<PB + GB, 256, 0, stream>>>(
        x, W0, gamma0, var0, Hs, N, srcp, dstp, gcur, part, E);

    // d3: per-bucket CSR build + rowptr + dinv + fp16 dinv-prefolded table Hh
    build_kernel<<<NBUCK, 256, 0, stream>>>(part, gcur, rowptr, dinv, csr, Hs, Hh, N);

    // d4: gather layer0 (fp16 rows, BN0 bias+relu) + gemm1 (BN1-scale folded) -> bufh (fp16)
    gather_gemm_h<64, true><<<(N + 31) / 32, 256, 0, stream>>>(
        Hh, rowptr, csr, dinv, b0, gamma0, beta0, mean0, var0,
        W1, gamma1, var1, bufh, N);

    // d5: gather layer1 (fp16 rows, BN1 bias+relu) + gemm2 (raw W2) -> t3h (fp16, 40ch)
    gather_gemm_h<40, false><<<(N + 31) / 32, 256, 0, stream>>>(
        bufh, rowptr, csr, dinv, b1, gamma1, beta1, mean1, var1,
        W2, nullptr, nullptr, t3h, N);

    // d6: final gather over t3h + b2 -> fp32 out
    gather_out_kernel<<<N / 50, 256, 0, stream>>>(t3h, rowptr, csr, dinv, b2, out, N);
}

// Round 5
// 231.055 us; speedup vs baseline: 1.2567x; 1.0154x over previous
//
#include <hip/hip_runtime.h>
#include <hip/hip_fp16.h>

#define N_NODES 50000
#define N_EDGES 800000
#define BN_EPS 1e-5f

#define NBUCK 196        // ceil(50000/256) buckets of 256 nodes
#define PART_CAP 6016    // per-bucket capacity; mean 4082, sd 64 -> 30 sigma margin
#define PB 196           // partition blocks (ceil(800000/4096))
#define GB 782           // gemm0 blocks (ceil(50000/64), 64-row tiles)

// exclusive 256-thread scan in LDS; s[] is scratch (256 ints). Returns exclusive prefix.
__device__ __forceinline__ int lds_scan256_excl(int* s, int t, int v) {
    s[t] = v;
    __syncthreads();
    for (int off = 1; off < 256; off <<= 1) {
        int x = (t >= off) ? s[t - off] : 0;
        __syncthreads();
        s[t] += x;
        __syncthreads();
    }
    return s[t] - v;
}

// phase of a source node id (4 ranges of 12500); exact floor(s/12500) for s<50000
__device__ __forceinline__ unsigned src_phase(unsigned s) {
    return (s * 42950u) >> 29;
}

// ---------------- GEMM body: Hs[r,M] = X[r,K] @ (W .* foldscale[c]) ----------------
// 64-row tile; 256 threads = 16x16, each 4x4; K chunked by 32. (proven shape: 978-block
// grid keeps ~4 blocks/CU. 8x8/256-row variant measured 76us @ 8% VALUBusy from
// parallelism collapse -- do not revisit.)
template <int K, int M, bool FOLD>
__device__ __forceinline__ void gemm_body(int bid, const float* __restrict__ X,
                                          const float* __restrict__ W,
                                          const float* __restrict__ gamma,
                                          const float* __restrict__ var,
                                          float* __restrict__ Hs, int n, float* lds) {
    constexpr int KC = 32;
    float* Xs = lds;                    // 64 x 36
    float* Ws = lds + 64 * 36;          // 32 x M
    float* bns = lds + 64 * 36 + 32 * M; // M bn scales
    int tid = threadIdx.x;
    int tx = tid & 15, ty = tid >> 4;
    int row0 = bid * 64;
    if (FOLD && tid < M) bns[tid] = gamma[tid] * rsqrtf(var[tid] + BN_EPS);
    __syncthreads();
    float acc[4][4] = {};
    for (int k0 = 0; k0 < K; k0 += KC) {
#pragma unroll
        for (int it = 0; it < 2; ++it) {
            int fi = tid + it * 256;            // 512 float4s
            int r = fi >> 3, q = fi & 7;
            int row = row0 + r;
            float4 v = make_float4(0.f, 0.f, 0.f, 0.f);
            if (row < n) v = *(const float4*)&X[(size_t)row * K + k0 + q * 4];
            *(float4*)&Xs[r * 36 + q * 4] = v;
        }
#pragma unroll
        for (int it = 0; it < 2; ++it) {
            int fi = tid + it * 256;            // 512 float4s (32*M/4 with M=64)
            int kk = fi >> 4, cw = (fi & 15) * 4;
            float4 w = *(const float4*)&W[(size_t)(k0 + kk) * M + cw];
            if (FOLD) { w.x *= bns[cw]; w.y *= bns[cw + 1]; w.z *= bns[cw + 2]; w.w *= bns[cw + 3]; }
            *(float4*)&Ws[kk * M + cw] = w;
        }
        __syncthreads();
        if (tx * 4 < M) {
#pragma unroll 8
            for (int kk = 0; kk < KC; ++kk) {
                float4 bv = *(float4*)&Ws[kk * M + tx * 4];
#pragma unroll
                for (int j = 0; j < 4; ++j) {
                    float a = Xs[(ty * 4 + j) * 36 + kk];
                    acc[j][0] += a * bv.x;
                    acc[j][1] += a * bv.y;
                    acc[j][2] += a * bv.z;
                    acc[j][3] += a * bv.w;
                }
            }
        }
        __syncthreads();
    }
    if (tx * 4 < M) {
#pragma unroll
        for (int j = 0; j < 4; ++j) {
            int r = row0 + ty * 4 + j;
            if (r < n) {
                float4 v = make_float4(acc[j][0], acc[j][1], acc[j][2], acc[j][3]);
                *(float4*)&Hs[(size_t)r * M + tx * 4] = v;
            }
        }
    }
}

// ---------------- dispatch 2: partition blocks first, then gemm0 blocks ----------------
__global__ __launch_bounds__(256, 4)
void fused_gemm0_partition_kernel(const float* __restrict__ X, const float* __restrict__ W,
                                  const float* __restrict__ gamma, const float* __restrict__ var,
                                  float* __restrict__ Hs, int n,
                                  const int* __restrict__ src, const int* __restrict__ dst,
                                  int* __restrict__ gcur, unsigned int* __restrict__ part,
                                  int nE) {
    __shared__ float lds[64 * 36 + 32 * 64 + 64];   // 17.7 KB
    if (blockIdx.x >= PB) {
        gemm_body<128, 64, true>(blockIdx.x - PB, X, W, gamma, var, Hs, n, lds);
        return;
    }
    // ---- partition branch: bin 4096 edges by dst>>8 ----
    int* lcnt  = (int*)lds;          // 196
    int* gbase = ((int*)lds) + 256;  // 196
    int t = threadIdx.x;
    int base = blockIdx.x * 4096;
    for (int i = t; i < NBUCK; i += 256) lcnt[i] = 0;
    __syncthreads();
    unsigned int val[16], pk[16];
#pragma unroll
    for (int i = 0; i < 16; ++i) {
        int e = base + i * 256 + t;
        if (e < nE) {
            unsigned s = (unsigned)src[e], d = (unsigned)dst[e];
            unsigned b = d >> 8;
            int r = atomicAdd(&lcnt[b], 1);
            val[i] = s | ((d & 255u) << 16);
            pk[i] = b | ((unsigned)r << 8);
        } else pk[i] = 0xffffffffu;
    }
    __syncthreads();
    for (int i = t; i < NBUCK; i += 256) gbase[i] = atomicAdd(&gcur[i], lcnt[i]);
    __syncthreads();
#pragma unroll
    for (int i = 0; i < 16; ++i) {
        if (pk[i] != 0xffffffffu) {
            unsigned b = pk[i] & 255u;
            unsigned p = (unsigned)gbase[b] + (pk[i] >> 8);
            if (p < PART_CAP) part[b * PART_CAP + p] = val[i];
        }
    }
}

// ---------------- dispatch 3: CSR build, phase-grouped lists + dinv + fp16 table ----------------
// Each node's neighbor list is grouped by src phase (4 ranges of 12500 nodes = 1.6 MB of
// fp16 table each). Gather grids are fully co-resident (1563 blocks ~ 1536 slots), so all
// blocks walk phase 0->3 in loose lockstep: hot table slice fits every XCD's 4 MB L2.
// Counting sort (histogram + prefix), NOT insertion sort (r3: +50us serial/divergent).
__global__ __launch_bounds__(256, 2)
void build_kernel(const unsigned int* __restrict__ part, const int* __restrict__ gcur,
                  int* __restrict__ rowptr, float* __restrict__ dinv,
                  unsigned short* __restrict__ csr, const float* __restrict__ Hs,
                  __half* __restrict__ Hh, int n) {
    __shared__ int sc[256], ns[256];
    __shared__ int nc4[256 * 4], cur4[256 * 4];
    __shared__ float sdinv[256];
    __shared__ unsigned short csr_lds[PART_CAP];
    __shared__ int sh_off, sh_ec;
    int b = blockIdx.x, t = threadIdx.x;
    int v = (t < NBUCK) ? gcur[t] : 0;
    int ex = lds_scan256_excl(sc, t, v);
    if (t == b) { sh_off = ex; sh_ec = v; }
    nc4[t * 4 + 0] = 0; nc4[t * 4 + 1] = 0; nc4[t * 4 + 2] = 0; nc4[t * 4 + 3] = 0;
    __syncthreads();
    int off = sh_off;
    int ec = sh_ec < PART_CAP ? sh_ec : PART_CAP;
    const unsigned int* pb = part + (size_t)b * PART_CAP;
    // histogram per (node, phase)
    for (int i = t; i < ec; i += 256) {
        unsigned w = pb[i];
        unsigned node = (w >> 16) & 255u;
        unsigned ph = src_phase(w & 0xffffu);
        atomicAdd(&nc4[node * 4 + ph], 1);
    }
    __syncthreads();
    int c0 = nc4[t * 4 + 0], c1 = nc4[t * 4 + 1], c2 = nc4[t * 4 + 2], c3 = nc4[t * 4 + 3];
    int c = c0 + c1 + c2 + c3;
    int nx = lds_scan256_excl(ns, t, c);
    cur4[t * 4 + 0] = nx;
    cur4[t * 4 + 1] = nx + c0;
    cur4[t * 4 + 2] = nx + c0 + c1;
    cur4[t * 4 + 3] = nx + c0 + c1 + c2;
    float dv = rsqrtf((float)c + 1.0f);   // +1 = self loop
    sdinv[t] = dv;
    int node = b * 256 + t;
    if (node < n) {
        rowptr[node] = off + nx;
        dinv[node] = dv;
    }
    if (b == NBUCK - 1 && t == 0) rowptr[n] = off + ec;
    __syncthreads();
    // scatter: phase-grouped within each node's sublist
    for (int i = t; i < ec; i += 256) {
        unsigned w = pb[i];
        unsigned nd = (w >> 16) & 255u;
        unsigned s = w & 0xffffu;
        unsigned ph = src_phase(s);
        int p = atomicAdd(&cur4[nd * 4 + ph], 1);
        csr_lds[p] = (unsigned short)s;
    }
    __syncthreads();
    for (int i = t; i < ec; i += 256) csr[off + i] = csr_lds[i];
    // ---- convert this bucket's Hs rows to fp16 with dinv prefold ----
    const float4* H4 = (const float4*)(Hs + (size_t)b * 256 * 64);
    for (int i = t; i < 4096; i += 256) {
        int nd = i >> 4;
        int nn = b * 256 + nd;
        if (nn < n) {
            float s = sdinv[nd];
            float4 x = H4[i];
            union { uint2 u; __half2 h[2]; } U;
            U.h[0] = __floats2half2_rn(x.x * s, x.y * s);
            U.h[1] = __floats2half2_rn(x.z * s, x.w * s);
            *(uint2*)&Hh[(size_t)nn * 64 + (i & 15) * 4] = U.u;
        }
    }
}

// ---------------- fused gather (fp16 table, BN+ReLU) + next-layer GEMM ----------------
// block = 32 nodes x 8 lanes; each lane owns 8 channels (16B fp16 loads).
template <int MOUT, bool FOLD_NEXT>
__global__ __launch_bounds__(256, 6)
void gather_gemm_h(const __half* __restrict__ Hh, const int* __restrict__ rowptr,
                   const unsigned short* __restrict__ csr, const float* __restrict__ dinv,
                   const float* __restrict__ bb, const float* __restrict__ gamma,
                   const float* __restrict__ beta, const float* __restrict__ mean,
                   const float* __restrict__ var,
                   const float* __restrict__ Wn, const float* __restrict__ gn,
                   const float* __restrict__ vn, __half* __restrict__ Hout, int n) {
    __shared__ float zs[32 * 68];          // pad 68: conflict-free z reads
    __shared__ float Ws[64 * MOUT];
    int t = threadIdx.x;
    int nd = t >> 3, l = t & 7;
    int d = blockIdx.x * 32 + nd;
    int c8 = l * 8;
    for (int i = t; i < 64 * MOUT; i += 256) {
        float w = Wn[i];
        if (FOLD_NEXT) { int c = i % MOUT; w *= gn[c] * rsqrtf(vn[c] + BN_EPS); }
        Ws[i] = w;
    }
    float acc[8] = {};
    float di = 0.f;
    int beg = 0, end = 0;
    if (d < n) {
        beg = rowptr[d]; end = rowptr[d + 1];
        di = dinv[d];
        union { uint4 u; __half2 h[4]; } S;
        S.u = *(const uint4*)&Hh[(size_t)d * 64 + c8];   // self loop (prescaled)
#pragma unroll
        for (int p = 0; p < 4; ++p) {
            float2 f = __half22float2(S.h[p]);
            acc[2 * p] += f.x; acc[2 * p + 1] += f.y;
        }
    }
    int e = beg;
    int head = (beg + 7) & ~7;             // align for uint4 index loads
    if (head > end) head = end;
    for (; e < head; ++e) {
        int s = csr[e];
        union { uint4 u; __half2 h[4]; } V;
        V.u = *(const uint4*)&Hh[(size_t)s * 64 + c8];
#pragma unroll
        for (int p = 0; p < 4; ++p) {
            float2 f = __half22float2(V.h[p]);
            acc[2 * p] += f.x; acc[2 * p + 1] += f.y;
        }
    }
    for (; e + 8 <= end; e += 8) {
        uint4 iv = *(const uint4*)&csr[e];   // 8 indices in one 16B load
        int sidx[8];
        sidx[0] = iv.x & 0xffff; sidx[1] = iv.x >> 16;
        sidx[2] = iv.y & 0xffff; sidx[3] = iv.y >> 16;
        sidx[4] = iv.z & 0xffff; sidx[5] = iv.z >> 16;
        sidx[6] = iv.w & 0xffff; sidx[7] = iv.w >> 16;
        uint4 vv[8];
#pragma unroll
        for (int q = 0; q < 8; ++q)
            vv[q] = *(const uint4*)&Hh[(size_t)sidx[q] * 64 + c8];
#pragma unroll
        for (int q = 0; q < 8; ++q) {
            union { uint4 u; __half2 h[4]; } V; V.u = vv[q];
#pragma unroll
            for (int p = 0; p < 4; ++p) {
                float2 f = __half22float2(V.h[p]);
                acc[2 * p] += f.x; acc[2 * p + 1] += f.y;
            }
        }
    }
    for (; e < end; ++e) {
        int s = csr[e];
        union { uint4 u; __half2 h[4]; } V;
        V.u = *(const uint4*)&Hh[(size_t)s * 64 + c8];
#pragma unroll
        for (int p = 0; p < 4; ++p) {
            float2 f = __half22float2(V.h[p]);
            acc[2 * p] += f.x; acc[2 * p + 1] += f.y;
        }
    }
    // BN bias + ReLU of current layer, write z tile to LDS
    if (d < n) {
#pragma unroll
        for (int q = 0; q < 8; ++q) {
            int cc = c8 + q;
            float s0 = gamma[cc] * rsqrtf(var[cc] + BN_EPS);
            float bias = (bb[cc] - mean[cc]) * s0 + beta[cc];
            zs[nd * 68 + cc] = fmaxf(acc[q] * di + bias, 0.0f);
        }
    }
    __syncthreads();
    // ---- gemm phase: Hout[d, c8..c8+7] = fp16(dinv[d] * sum_k zs[nd][k] * Ws[k][c]) ----
    if (c8 < MOUT && d < n) {
        float o[8] = {};
        for (int k0 = 0; k0 < 64; k0 += 4) {
            float4 zq = *(const float4*)&zs[nd * 68 + k0];
#pragma unroll
            for (int j = 0; j < 4; ++j) {
                float zk = (&zq.x)[j];
                float4 w0 = *(const float4*)&Ws[(k0 + j) * MOUT + c8];
                float4 w1 = *(const float4*)&Ws[(k0 + j) * MOUT + c8 + 4];
                o[0] += zk * w0.x; o[1] += zk * w0.y; o[2] += zk * w0.z; o[3] += zk * w0.w;
                o[4] += zk * w1.x; o[5] += zk * w1.y; o[6] += zk * w1.z; o[7] += zk * w1.w;
            }
        }
        union { uint4 u; __half2 h[4]; } O;
#pragma unroll
        for (int p = 0; p < 4; ++p)
            O.h[p] = __floats2half2_rn(o[2 * p] * di, o[2 * p + 1] * di);
        *(uint4*)&Hout[(size_t)d * MOUT + c8] = O.u;
    }
}

// ---------------- final gather over fp16 40-ch rows; fp32 out ----------------
// block = 50 nodes x 5 lanes (250 active threads); lane owns 8 channels (16B loads).
__global__ __launch_bounds__(256, 8)
void gather_out_kernel(const __half* __restrict__ t3, const int* __restrict__ rowptr,
                       const unsigned short* __restrict__ csr, const float* __restrict__ dinv,
                       const float* __restrict__ bias, float* __restrict__ out, int n) {
    int t = threadIdx.x;
    if (t >= 250) return;
    int nd = t / 5, l = t % 5;
    int d = blockIdx.x * 50 + nd;
    if (d >= n) return;
    int c8 = l * 8;
    int beg = rowptr[d], end = rowptr[d + 1];
    float di = dinv[d];
    float acc[8];
    {
        union { uint4 u; __half2 h[4]; } S;
        S.u = *(const uint4*)&t3[(size_t)d * 40 + c8];
#pragma unroll
        for (int p = 0; p < 4; ++p) {
            float2 f = __half22float2(S.h[p]);
            acc[2 * p] = f.x; acc[2 * p + 1] = f.y;
        }
    }
    int e = beg;
    int head = (beg + 7) & ~7;
    if (head > end) head = end;
    for (; e < head; ++e) {
        int s = csr[e];
        union { uint4 u; __half2 h[4]; } V;
        V.u = *(const uint4*)&t3[(size_t)s * 40 + c8];
#pragma unroll
        for (int p = 0; p < 4; ++p) {
            float2 f = __half22float2(V.h[p]);
            acc[2 * p] += f.x; acc[2 * p + 1] += f.y;
        }
    }
    for (; e + 8 <= end; e += 8) {
        uint4 iv = *(const uint4*)&csr[e];
        int sidx[8];
        sidx[0] = iv.x & 0xffff; sidx[1] = iv.x >> 16;
        sidx[2] = iv.y & 0xffff; sidx[3] = iv.y >> 16;
        sidx[4] = iv.z & 0xffff; sidx[5] = iv.z >> 16;
        sidx[6] = iv.w & 0xffff; sidx[7] = iv.w >> 16;
        uint4 vv[8];
#pragma unroll
        for (int q = 0; q < 8; ++q)
            vv[q] = *(const uint4*)&t3[(size_t)sidx[q] * 40 + c8];
#pragma unroll
        for (int q = 0; q < 8; ++q) {
            union { uint4 u; __half2 h[4]; } V; V.u = vv[q];
#pragma unroll
            for (int p = 0; p < 4; ++p) {
                float2 f = __half22float2(V.h[p]);
                acc[2 * p] += f.x; acc[2 * p + 1] += f.y;
            }
        }
    }
    for (; e < end; ++e) {
        int s = csr[e];
        union { uint4 u; __half2 h[4]; } V;
        V.u = *(const uint4*)&t3[(size_t)s * 40 + c8];
#pragma unroll
        for (int p = 0; p < 4; ++p) {
            float2 f = __half22float2(V.h[p]);
            acc[2 * p] += f.x; acc[2 * p + 1] += f.y;
        }
    }
    float4 r0, r1;
    r0.x = acc[0] * di + bias[c8 + 0];
    r0.y = acc[1] * di + bias[c8 + 1];
    r0.z = acc[2] * di + bias[c8 + 2];
    r0.w = acc[3] * di + bias[c8 + 3];
    r1.x = acc[4] * di + bias[c8 + 4];
    r1.y = acc[5] * di + bias[c8 + 5];
    r1.z = acc[6] * di + bias[c8 + 6];
    r1.w = acc[7] * di + bias[c8 + 7];
    *(float4*)&out[(size_t)d * 40 + c8] = r0;
    *(float4*)&out[(size_t)d * 40 + c8 + 4] = r1;
}

extern "C" void kernel_launch(void* const* d_in, const int* in_sizes, int n_in,
                              void* d_out, int out_size, void* d_ws, size_t ws_size,
                              hipStream_t stream) {
    const float* x      = (const float*)d_in[0];
    const int*   ei     = (const int*)d_in[1];
    const float* W0     = (const float*)d_in[2];
    const float* b0     = (const float*)d_in[3];
    const float* gamma0 = (const float*)d_in[4];
    const float* beta0  = (const float*)d_in[5];
    const float* mean0  = (const float*)d_in[6];
    const float* var0   = (const float*)d_in[7];
    const float* W1     = (const float*)d_in[8];
    const float* b1     = (const float*)d_in[9];
    const float* gamma1 = (const float*)d_in[10];
    const float* beta1  = (const float*)d_in[11];
    const float* mean1  = (const float*)d_in[12];
    const float* var1   = (const float*)d_in[13];
    const float* W2     = (const float*)d_in[14];
    const float* b2     = (const float*)d_in[15];
    float* out = (float*)d_out;

    const int* srcp = ei;
    const int* dstp = ei + N_EDGES;
    const int N = N_NODES, E = N_EDGES;

    // workspace carve-up (bytes, 16B-aligned). Total footprint 27.6 MB.
    char* ws = (char*)d_ws;
    int*            gcur   = (int*)(ws + 0);          // 784 B
    int*            rowptr = (int*)(ws + 1024);       // 200004
    float*          dinv   = (float*)(ws + 202240);   // 200000
    unsigned short* csr    = (unsigned short*)(ws + 402688);   // 1.6 MB
    float*          Hs     = (float*)(ws + 2002944);  // 12.8 MB fp32 gemm0 out (dead after d3)
    __half*         bufh   = (__half*)(ws + 2002944); // 6.4 MB, aliases Hs (written in d4)
    __half*         t3h    = (__half*)(ws + 8402944); // 4.0 MB, aliases Hs tail (written in d5)
    unsigned int*   part   = (unsigned int*)(ws + 14802944);   // 4.7 MB (dead after d3)
    __half*         Hh     = (__half*)(ws + 21202944);         // 6.4 MB fp16 prescaled table

    hipMemsetAsync(gcur, 0, NBUCK * sizeof(int), stream);

    // d2: partition (blocks 0..195) + gemm0 (BN0-folded, 64-row tiles) in one dispatch
    fused_gemm0_partition_kernel<<<PB + GB, 256, 0, stream>>>(
        x, W0, gamma0, var0, Hs, N, srcp, dstp, gcur, part, E);

    // d3: CSR build with 4-phase src grouping + rowptr + dinv + fp16 prefolded table Hh
    build_kernel<<<NBUCK, 256, 0, stream>>>(part, gcur, rowptr, dinv, csr, Hs, Hh, N);

    // d4: gather layer0 (fp16 rows, BN0 bias+relu) + gemm1 (BN1-scale folded) -> bufh (fp16)
    gather_gemm_h<64, true><<<(N + 31) / 32, 256, 0, stream>>>(
        Hh, rowptr, csr, dinv, b0, gamma0, beta0, mean0, var0,
        W1, gamma1, var1, bufh, N);

    // d5: gather layer1 (fp16 rows, BN1 bias+relu) + gemm2 (raw W2) -> t3h (fp16, 40ch)
    gather_gemm_h<40, false><<<(N + 31) / 32, 256, 0, stream>>>(
        bufh, rowptr, csr, dinv, b1, gamma1, beta1, mean1, var1,
        W2, nullptr, nullptr, t3h, N);

    // d6: final gather over t3h + b2 -> fp32 out
    gather_out_kernel<<<N / 50, 256, 0, stream>>>(t3h, rowptr, csr, dinv, b2, out, N);
}